// Round 13
// baseline (644.163 us; speedup 1.0000x reference)
//
#include <hip/hip_runtime.h>
#include <cstddef>

#define Bv 4
#define Nv 24
#define NTv 16
#define Tv 64
#define NP 25
#define NEGF (-1e30f)

typedef __attribute__((ext_vector_type(8))) short short8v;
typedef __attribute__((ext_vector_type(4))) float f32x4;
union FragU { unsigned u[4]; short8v s; };

// ---------------- workspace layout (floats) ----------------
// betaA layout: [B][25 l][25 r][24 head][16 sym]  (head-major for coalesced lane reads)
#define BETAA_OFF 0         // [B][25][25][24 head][16 sym]            960000
#define BETAU_OFF 960000    // [B][25][25][64 sym]                     160000
#define RNT_OFF   1120000   // bf16-packed: [B][2 d][24 h][16 A][128]  u32
#define T0_OFF    1906432   // [B][24 h][24 p][16 sL][16 A]            589824
#define T1_OFF    2496256   // [B][24 h][24 p][16 sR][16 A]            589824
#define T0L_OFF   3086080   // [B][24 h][16 sR][16 A]                  24576
#define T1R_OFF   3110656   // [B][24 h][16 sL][16 A]                  24576
#define D0_OFF    3135232   // [B][24 l][16 A]                         1536
#define D1_OFF    3136768   // [B][24 l][16 A]                         1536
#define EU_OFF    3138304   // [B][24 p][48 j]  exp(unary terminal)    4608
#define CELLF_OFF 3142912   // [B][25*25] int per-cell done flags      2500
#define WS_NEED   3145412

// sweep-free publication (R10-verified): relaxed agent-scope atomic store lands
// the value at the device coherence point; readers first-touch after the flag.
__device__ __forceinline__ void publish(float* p, float v) {
  __hip_atomic_store(p, v, __ATOMIC_RELAXED, __HIP_MEMORY_SCOPE_AGENT);
}

__device__ __forceinline__ unsigned packbf2(float lo, float hi) {
  unsigned bl = __float_as_uint(lo), bh = __float_as_uint(hi);
  bl = (bl + 0x7FFFu + ((bl >> 16) & 1u)) >> 16;   // RNE
  bh = (bh + 0x7FFFu + ((bh >> 16) & 1u)) >> 16;
  return (bh << 16) | bl;
}

// ---- init: width-1 betau + exp(unary) table + cell flags ----
__global__ void init_kernel(const float* __restrict__ unary, float* __restrict__ betau,
                            float* __restrict__ Eu, int* __restrict__ cellF) {
  int t = blockIdx.x * blockDim.x + threadIdx.x;
  if (t < Bv * NP * NP) cellF[t] = 0;
  if (t >= Bv * Nv * 48) return;
  int i = t % 48, kk = (t / 48) % Nv, b = t / (48 * Nv);
  float u = unary[(size_t)(b * Nv + kk) * Tv + 16 + i];
  betau[((size_t)(b * NP + kk) * NP + (kk + 1)) * Tv + 16 + i] = u;
  Eu[(size_t)(b * Nv + kk) * 48 + i] = __expf(u);
}

// ---- fused prep: block per (b,A,h); coalesced 32KB rule read; all precontractions ----
__global__ __launch_bounds__(256) void prep_kernel(
    const float* __restrict__ rule, const float* __restrict__ Eu,
    unsigned* __restrict__ RNTh, float* __restrict__ T0, float* __restrict__ T1,
    float* __restrict__ T0L, float* __restrict__ T1R,
    float* __restrict__ D0, float* __restrict__ D1) {
  const int h = blockIdx.x, A = blockIdx.y, b = blockIdx.z;
  const int t = threadIdx.x;  // 256
  __shared__ float er0[64 * 65];
  __shared__ float er1[64 * 65];
  __shared__ float E[24 * 48];
  __shared__ float red[256];

  for (int i = t; i < 24 * 48; i += 256) E[i] = Eu[(size_t)b * (24 * 48) + i];
  const float* rb = rule + (size_t)((b * NTv + A) * Nv + h) * 8192;
#pragma unroll
  for (int i = 0; i < 8; ++i) {
    int lin = i * 1024 + t * 4;  // = sL*128 + sR*2 + d
    float4 v = *(const float4*)(rb + lin);
    int sL = lin >> 7, rem = (lin & 127) >> 1;
    er0[sL * 65 + rem] = __expf(v.x);
    er1[sL * 65 + rem] = __expf(v.y);
    er0[sL * 65 + rem + 1] = __expf(v.z);
    er1[sL * 65 + rem + 1] = __expf(v.w);
  }
  __syncthreads();
  // RNTh (A-major, bf16 pairs over sR): [b][d][h][A][sL*8 + sRp]
  {
    unsigned* dst0 = RNTh + (((size_t)(b * 2 + 0) * Nv + h) * NTv + A) * 128;
    unsigned* dst1 = RNTh + (((size_t)(b * 2 + 1) * Nv + h) * NTv + A) * 128;
    if (t < 128) {
      int sL = t >> 3, sRp = t & 7;
      dst0[t] = packbf2(er0[sL * 65 + 2 * sRp], er0[sL * 65 + 2 * sRp + 1]);
    } else {
      int t2 = t - 128;
      int sL = t2 >> 3, sRp = t2 & 7;
      dst1[t2] = packbf2(er1[sL * 65 + 2 * sRp], er1[sL * 65 + 2 * sRp + 1]);
    }
  }
  for (int o = t; o < 384; o += 256) {
    int p = o >> 4, sL = o & 15;
    const float* Ep = E + p * 48;
    const float* r0 = er0 + sL * 65 + 16;
    float acc = 0.f;
#pragma unroll 8
    for (int j = 0; j < 48; ++j) acc += Ep[j] * r0[j];
    T0[(((size_t)(b * Nv + h) * Nv + p) * NTv + sL) * NTv + A] = acc;
  }
  for (int o = t; o < 384; o += 256) {
    int p = o >> 4, sR = o & 15;
    const float* Ep = E + p * 48;
    float acc = 0.f;
#pragma unroll 8
    for (int i = 0; i < 48; ++i) acc += Ep[i] * er1[(16 + i) * 65 + sR];
    T1[(((size_t)(b * Nv + h) * Nv + p) * NTv + sR) * NTv + A] = acc;
  }
  if (t < 16) {
    float acc = 0.f;
    for (int i = 0; i < 48; ++i) acc += er0[(16 + i) * 65 + t];
    T0L[((size_t)(b * Nv + h) * NTv + t) * NTv + A] = acc;
  } else if (t < 32) {
    int sL = t - 16;
    float acc = 0.f;
    for (int j = 0; j < 48; ++j) acc += er1[sL * 65 + 16 + j];
    T1R[((size_t)(b * Nv + h) * NTv + sL) * NTv + A] = acc;
  }
  float acc0 = 0.f, acc1 = 0.f;
  const int hp = (h + 1 < 24) ? h + 1 : 0, hm = (h >= 1) ? h - 1 : 0;
  for (int e = t; e < 2304; e += 256) {
    int i = e / 48, j = e % 48;
    float r0 = er0[(16 + i) * 65 + 16 + j];
    float r1 = er1[(16 + i) * 65 + 16 + j];
    acc0 += E[hp * 48 + j] * r0;
    acc1 += E[hm * 48 + i] * r1;
  }
  red[t] = acc0;
  __syncthreads();
  if (t < 64) {
    float s = red[t] + red[t + 64] + red[t + 128] + red[t + 192];
#pragma unroll
    for (int off = 32; off; off >>= 1) s += __shfl_xor(s, off, 64);
    if (t == 0 && h <= 22) D0[((size_t)b * Nv + h) * NTv + A] = s;
  }
  __syncthreads();
  red[t] = acc1;
  __syncthreads();
  if (t < 64) {
    float s = red[t] + red[t + 64] + red[t + 128] + red[t + 192];
#pragma unroll
    for (int off = 32; off; off >>= 1) s += __shfl_xor(s, off, 64);
    if (t == 0 && h >= 1) D1[((size_t)b * Nv + (h - 1)) * NTv + A] = s;
  }
}

__device__ __forceinline__ void edge_dot(float v0, float v1, float v2, float v3,
                                         const float* Tb, float& sh, float& S) {
  float mx = fmaxf(fmaxf(v0, v1), fmaxf(v2, v3));
  mx = fmaxf(mx, __shfl_xor(mx, 1, 64));
  mx = fmaxf(mx, __shfl_xor(mx, 2, 64));
  float dot = __expf(v0 - mx) * Tb[0] + __expf(v1 - mx) * Tb[16] +
              __expf(v2 - mx) * Tb[32] + __expf(v3 - mx) * Tb[48];
  dot += __shfl_xor(dot, 1, 64);
  dot += __shfl_xor(dot, 2, 64);
  sh = mx;
  S = dot;
}

// ---- R11-verbatim cell body, parameterized by column (own LDS) and edge source ----
// eChart/eBu point at chart(l, r-1) row / betau(l, r-1) NT row -- either another
// block's published global rows (edgePollIdx >= 0: poll the flag first) or the
// own block's other column's LDS rows (edgePollIdx < 0: barrier-ordered, no poll).
__device__ __forceinline__ void cell_body(
    int b, int r, int l, int tid,
    float (*chartOwn)[384], float (*buOwn)[16],
    const float* eChart, const float* eBu, int edgePollIdx, int* flagb,
    float* U0, float* U1, float* pM, float* pS, float* sTmp,
    const float* __restrict__ unary, float* __restrict__ betaA, float* __restrict__ betau,
    const unsigned* __restrict__ RNTh, const float* __restrict__ T0,
    const float* __restrict__ T1, const float* __restrict__ T0L,
    const float* __restrict__ T1R, const float* __restrict__ D0,
    const float* __restrict__ D1) {
  const int W = r - l;
  const int wv = tid >> 6, lane = tid & 63;
  const int sym = lane & 15;          // A-row / B-col index
  const int mBlk = (lane >> 4) * 8;   // k-offset of this lane's 8 elements

  if (W >= 3) {
    // interior deps (slack >= 1): cells (l, m) for m in [l+2, r-2]
    if (tid < W - 3) {
      const int m = l + 2 + tid;
      while (__hip_atomic_load(&flagb[l * NP + m], __ATOMIC_RELAXED,
                               __HIP_MEMORY_SCOPE_AGENT) == 0)
        __builtin_amdgcn_s_sleep(1);
    }
    __syncthreads();  // also orders prior cells' LDS epilogue writes
  }

  float Gp[4];
  // ---- Phase A: gather, global-max shift, exp, 1 MFMA per (head,dir) pair ----
#pragma unroll
  for (int pi = 0; pi < 4; ++pi) {
    const int p = wv + 12 * pi;
    if (p < 2 * W) {
      const int hh = p >> 1, d = p & 1, hcol = l + hh;
      int mst, cnt;
      if (d) { mst = l + 2; cnt = min(l + hh, r - 2) - mst + 1; }
      else   { mst = max(l + hh + 1, l + 2); cnt = (r - 2) - mst + 1; }
      if (cnt < 0) cnt = 0;
      float* Ua = (d ? U1 : U0) + hh * 256;
      if (cnt == 0) {
#pragma unroll
        for (int reg = 0; reg < 4; ++reg)
          Ua[((lane >> 4) * 4 + reg) * 16 + sym] = 0.f;
        Gp[pi] = -2e30f;
      } else {
        float Lv[8], Rv[8];
        if (d) {  // L = betau(l,m)[sym] (global rows), R = chart(m,r) (own LDS)
          const size_t lb = ((size_t)(b * NP + l) * NP + mst) * Tv + sym;
#pragma unroll
          for (int j = 0; j < 8; ++j) {
            int mi = mBlk + j;
            Lv[j] = (mi < cnt) ? betau[lb + (size_t)mi * Tv] : NEGF;
            Rv[j] = (mi < cnt) ? chartOwn[mst + mi][hcol * 16 + sym] : NEGF;
          }
        } else {  // L = chart(l,m) (global rows), R = betau(m,r) (own LDS)
          const size_t lb = ((size_t)(b * NP + l) * NP + mst) * 384 + hcol * 16 + sym;
#pragma unroll
          for (int j = 0; j < 8; ++j) {
            int mi = mBlk + j;
            Lv[j] = (mi < cnt) ? betaA[lb + (size_t)mi * 384] : NEGF;
            Rv[j] = (mi < cnt) ? buOwn[mst + mi][sym] : NEGF;
          }
        }
        float mxL = NEGF, mxR = NEGF;
#pragma unroll
        for (int j = 0; j < 8; ++j) { mxL = fmaxf(mxL, Lv[j]); mxR = fmaxf(mxR, Rv[j]); }
#pragma unroll
        for (int off = 1; off < 64; off <<= 1) {
          mxL = fmaxf(mxL, __shfl_xor(mxL, off, 64));
          mxR = fmaxf(mxR, __shfl_xor(mxR, off, 64));
        }
        FragU fa, fb;
#pragma unroll
        for (int jj = 0; jj < 4; ++jj) {
          int m0i = mBlk + 2 * jj, m1i = m0i + 1;
          float e0 = (m0i < cnt) ? __expf(Lv[2 * jj] - mxL) : 0.f;
          float e1 = (m1i < cnt) ? __expf(Lv[2 * jj + 1] - mxL) : 0.f;
          fa.u[jj] = packbf2(e0, e1);
          float f0 = (m0i < cnt) ? __expf(Rv[2 * jj] - mxR) : 0.f;
          float f1 = (m1i < cnt) ? __expf(Rv[2 * jj + 1] - mxR) : 0.f;
          fb.u[jj] = packbf2(f0, f1);
        }
        f32x4 z = {0.f, 0.f, 0.f, 0.f};
        f32x4 dU = __builtin_amdgcn_mfma_f32_16x16x32_bf16(fa.s, fb.s, z, 0, 0, 0);
#pragma unroll
        for (int reg = 0; reg < 4; ++reg)
          Ua[((lane >> 4) * 4 + reg) * 16 + sym] = dU[reg];
        Gp[pi] = mxL + mxR;
      }
    }
  }

  // ---- slack-0/1 edge poll (cross-block edges only; LDS edges barrier-ordered) ----
  if (W >= 3 && edgePollIdx >= 0) {
    while (__hip_atomic_load(&flagb[edgePollIdx], __ATOMIC_RELAXED,
                             __HIP_MEMORY_SCOPE_AGENT) == 0)
      __builtin_amdgcn_s_sleep(1);
  }

  // ---- Phase B: 8-MFMA matvec per pair + edges ----
#pragma unroll
  for (int pi = 0; pi < 4; ++pi) {
    const int p = wv + 12 * pi;
    if (p < 2 * W) {
      const int hh = p >> 1, d = p & 1, h = l + hh;
      const float* Ua = (d ? U1 : U0) + hh * 256;
      const unsigned* Rb = RNTh + (((size_t)(b * 2 + d) * Nv + h) * NTv + sym) * 128;
      f32x4 acc4 = {0.f, 0.f, 0.f, 0.f};
#pragma unroll
      for (int kk = 0; kk < 8; ++kk) {
        uint4 ar = *(const uint4*)(Rb + kk * 16 + (lane >> 4) * 4);
        FragU fa, fb;
        fa.u[0] = ar.x; fa.u[1] = ar.y; fa.u[2] = ar.z; fa.u[3] = ar.w;
        if (sym == 0) {
          const float* up = Ua + kk * 32 + mBlk;
#pragma unroll
          for (int jj = 0; jj < 4; ++jj) fb.u[jj] = packbf2(up[2 * jj], up[2 * jj + 1]);
        } else {
          fb.u[0] = 0; fb.u[1] = 0; fb.u[2] = 0; fb.u[3] = 0;
        }
        acc4 = __builtin_amdgcn_mfma_f32_16x16x32_bf16(fa.s, fb.s, acc4, 0, 0, 0);
      }
      // broadcast acc[A] (rows live in col-0 lanes) to (A,q) edge layout
      const int A = lane >> 2, q = lane & 3;
      const int src = (A >> 2) << 4;
      float c0 = __shfl(acc4[0], src, 64);
      float c1 = __shfl(acc4[1], src, 64);
      float c2 = __shfl(acc4[2], src, 64);
      float c3 = __shfl(acc4[3], src, 64);
      const int sel = A & 3;
      float acc = (sel == 0) ? c0 : (sel == 1) ? c1 : (sel == 2) ? c2 : c3;
      float Mi = Gp[pi];
      float sh2 = NEGF, S2 = 0.f, sh3 = NEGF, S3 = 0.f;
      if (W >= 3) {
        if (d == 0) {
          if (hh < W - 1) {  // split m=r-1: chart(l,r-1) x terminal via T0
            const float* Tb = T0 + (((size_t)(b * Nv + h) * Nv + (r - 1)) * NTv + 4 * q) * NTv + A;
            float4 e4 = *(const float4*)(eChart + (size_t)h * 16 + 4 * q);
            edge_dot(e4.x, e4.y, e4.z, e4.w, Tb, sh2, S2);
          }
          if (hh == 0) {     // split m=l+1: terminal x betau(l+1,r) via T0L (own, LDS)
            const float* Tb = T0L + ((size_t)(b * Nv + l) * NTv + 4 * q) * NTv + A;
            const float* u4 = &buOwn[l + 1][4 * q];
            edge_dot(u4[0], u4[1], u4[2], u4[3], Tb, sh3, S3);
          }
        } else {
          if (hh >= 1) {     // split m=l+1: terminal x chart(l+1,r) via T1 (own, LDS)
            const float* Tb = T1 + (((size_t)(b * Nv + h) * Nv + l) * NTv + 4 * q) * NTv + A;
            const float* e4 = &chartOwn[l + 1][h * 16 + 4 * q];
            edge_dot(e4[0], e4[1], e4[2], e4[3], Tb, sh2, S2);
          }
          if (hh == W - 1) { // split m=r-1: betau(l,r-1) x terminal via T1R
            const float* Tb = T1R + ((size_t)(b * Nv + (r - 1)) * NTv + 4 * q) * NTv + A;
            float4 u4 = *(const float4*)(eBu + 4 * q);
            edge_dot(u4.x, u4.y, u4.z, u4.w, Tb, sh3, S3);
          }
        }
      } else {  // W == 2
        if (d == 0 && hh == 0) { sh2 = 0.f; S2 = D0[((size_t)b * Nv + l) * NTv + A]; }
        if (d == 1 && hh == 1) { sh2 = 0.f; S2 = D1[((size_t)b * Nv + l) * NTv + A]; }
      }
      float Mf = fmaxf(Mi, fmaxf(sh2, sh3));
      float Sf = acc * __expf(Mi - Mf) + S2 * __expf(sh2 - Mf) + S3 * __expf(sh3 - Mf);
      if (q == 0) {
        pM[(d * 24 + hh) * 16 + A] = Mf;
        pS[(d * 24 + hh) * 16 + A] = Sf;
      }
    }
  }
  __syncthreads();

  // combine dirs; publish betaA + fill own chart row; prep betau input
  if (tid < 384) {
    int A2 = tid & 15, hh = tid >> 4;
    if (hh < W) {
      float M0 = pM[(0 * 24 + hh) * 16 + A2], S0 = pS[(0 * 24 + hh) * 16 + A2];
      float M1 = pM[(1 * 24 + hh) * 16 + A2], S1 = pS[(1 * 24 + hh) * 16 + A2];
      float nm = fmaxf(M0, M1);
      float s = S0 * __expf(M0 - nm) + S1 * __expf(M1 - nm);
      float val = nm + __logf(s);
      publish(&betaA[((size_t)(b * NP + l) * NP + r) * 384 + (l + hh) * 16 + A2], val);
      chartOwn[l][(l + hh) * 16 + A2] = val;
      sTmp[A2 * 24 + hh] = val + unary[(size_t)(b * Nv + (l + hh)) * Tv + A2];
    }
  }
  __syncthreads();  // sTmp ready; betaA publishes drained (implicit vmcnt(0))
  if (tid < 16) {
    float mx = NEGF;
    for (int x = 0; x < W; ++x) mx = fmaxf(mx, sTmp[tid * 24 + x]);
    float s = 0.f;
    for (int x = 0; x < W; ++x) s += __expf(sTmp[tid * 24 + x] - mx);
    float val = mx + __logf(s);
    publish(&betau[((size_t)(b * NP + l) * NP + r) * Tv + tid], val);
    buOwn[l][tid] = val;
  }
  if (tid == 0) {
    asm volatile("s_waitcnt vmcnt(0)" ::: "memory");  // drain wave0 betau publishes
    __hip_atomic_store(&flagb[l * NP + r], 1, __ATOMIC_RELAXED,
                       __HIP_MEMORY_SCOPE_AGENT);
  }
}

// ---- paired-column persistent kernel: block g owns columns 2g+1, 2g+2 ----
// Schedule A0,B0,A1,B1,...: B-cells' slack-0 edge (l, rB-1)=(l, rA) is the own
// A column (LDS, no hop); A-cells' edge (l, rA-1) is the neighbor's B column
// with one super-period of slack -> the LLC hand-off hides under own compute.
__global__ __launch_bounds__(768) void width_all_kernel(
    const float* __restrict__ unary, float* __restrict__ betaA, float* __restrict__ betau,
    const unsigned* __restrict__ RNTh, const float* __restrict__ T0, const float* __restrict__ T1,
    const float* __restrict__ T0L, const float* __restrict__ T1R,
    const float* __restrict__ D0, const float* __restrict__ D1,
    const float* __restrict__ root, float* __restrict__ out, int* __restrict__ cellF) {
  const int g = blockIdx.x, b = blockIdx.y;
  const int tid = threadIdx.x;
  int* flagb = cellF + b * (NP * NP);

  __shared__ float chartA[22][384], chartB[23][384];
  __shared__ float buA[22][16], buB[23][16];
  __shared__ float U0[24 * 256], U1[24 * 256];
  __shared__ float pM[2 * 24 * 16], pS[2 * 24 * 16];
  __shared__ float sTmp[16 * 24];

  if (g == 0) {  // column 2: single W=2 cell (0,2), no deps
    cell_body(b, 2, 0, tid, chartB, buB, betaA, betau, -1, flagb,
              U0, U1, pM, pS, sTmp, unary, betaA, betau,
              RNTh, T0, T1, T0L, T1R, D0, D1);
    return;
  }

  const int rA = 2 * g + 1, rB = 2 * g + 2;
  const int nA = rA - 1, nB = rB - 1;
  for (int i = 0; i < nB; ++i) {
    if (i < nA) {
      const int l = rA - 2 - i;
      cell_body(b, rA, l, tid, chartA, buA,
                betaA + ((size_t)(b * NP + l) * NP + (rA - 1)) * 384 - (size_t)0,
                betau + ((size_t)(b * NP + l) * NP + (rA - 1)) * Tv,
                l * NP + (rA - 1), flagb, U0, U1, pM, pS, sTmp,
                unary, betaA, betau, RNTh, T0, T1, T0L, T1R, D0, D1);
    }
    {
      const int l = rB - 2 - i;
      const int lc = (l < 22) ? l : 0;  // W=2 cell never reads edges; clamp ptr
      cell_body(b, rB, l, tid, chartB, buB,
                &chartA[lc][0], &buA[lc][0], -1, flagb,
                U0, U1, pM, pS, sTmp,
                unary, betaA, betau, RNTh, T0, T1, T0L, T1R, D0, D1);
    }
  }

  // ---- final: block owning column 24 (g=11) emits out[b] from cell (0,24) ----
  if (g == 11) {
    __syncthreads();
    if (tid == 0) {
      float vals[NTv];
      float mx = NEGF;
#pragma unroll
      for (int A = 0; A < NTv; ++A) {
        float v = buB[0][A] + root[b * NTv + A];
        vals[A] = v;
        mx = fmaxf(mx, v);
      }
      float s = 0.f;
#pragma unroll
      for (int A = 0; A < NTv; ++A) s += __expf(vals[A] - mx);
      out[b] = mx + __logf(s);
    }
  }
}

// NOTE: eChart for A-cells above points at betaA row base; the body adds h*16.
// For B-cells eChart points at chartA[l] whose layout [head*16+sym] matches.

// ---- fallback width kernel (direct rule reads, self-consistent layout) ----
__global__ __launch_bounds__(768) void width_kernel_fb(
    const float* __restrict__ unary, const float* __restrict__ rule,
    float* __restrict__ betaA, float* __restrict__ betau, int W) {
  const int l = blockIdx.x, b = blockIdx.y;
  const int r = l + W;
  const int tid = threadIdx.x;
  const int sub = tid & 1;
  const int pid = tid >> 1;
  const int A = pid & 15;
  const int hh = pid >> 4;
  const int h = l + hh;
  const bool act = (hh < W);
  const int sA = tid & 15, sH = tid >> 4;

  __shared__ float sER0[48], sEL1[48];
  __shared__ float sCL0[16 * 24], sCR1[16 * 24];
  __shared__ float sMaxL0[24], sMaxR1[24];
  __shared__ float sShR0, sShL1;
  __shared__ float sTmp[16 * 24];

  float runM = NEGF, runS = 0.f;
  for (int m = l + 1; m < r; ++m) {
    const int wl = m - l, wr = r - m;
    if (tid < 64) {
      const int n = (wr == 1) ? 48 : 16, s0 = (wr == 1) ? 16 : 0;
      float v = (tid < n) ? betau[(size_t)((b * NP + m) * NP + r) * Tv + s0 + tid] : NEGF;
      float mx = v;
#pragma unroll
      for (int off = 32; off; off >>= 1) mx = fmaxf(mx, __shfl_xor(mx, off, 64));
      if (tid == 0) sShR0 = mx;
      if (tid < n) sER0[tid] = v - mx;
    } else if (tid < 128) {
      const int j = tid - 64;
      const int n = (wl == 1) ? 48 : 16, s0 = (wl == 1) ? 16 : 0;
      float v = (j < n) ? betau[(size_t)((b * NP + l) * NP + m) * Tv + s0 + j] : NEGF;
      float mx = v;
#pragma unroll
      for (int off = 32; off; off >>= 1) mx = fmaxf(mx, __shfl_xor(mx, off, 64));
      if (j == 0) sShL1 = mx;
      if (j < n) sEL1[j] = v - mx;
    }
    if (tid < 384) {
      if (wl > 1 && sH < wl) {
        float v = betaA[(size_t)((b * NP + l) * NP + m) * 384 + sA * Nv + (l + sH)];
        float mx = v;
#pragma unroll
        for (int off = 8; off; off >>= 1) mx = fmaxf(mx, __shfl_xor(mx, off, 16));
        if (sA == 0) sMaxL0[sH] = mx;
        sCL0[sA * Nv + sH] = v - mx;
      }
      if (wr > 1 && sH >= wl && sH < W) {
        float v = betaA[(size_t)((b * NP + m) * NP + r) * 384 + sA * Nv + (l + sH)];
        float mx = v;
#pragma unroll
        for (int off = 8; off; off >>= 1) mx = fmaxf(mx, __shfl_xor(mx, off, 16));
        if (sA == 0) sMaxR1[sH] = mx;
        sCR1[sA * Nv + sH] = v - mx;
      }
    }
    __syncthreads();
    if (act) {
      if (hh < wl && (wl > 1 || hh == 0)) {
        const int nL = (wl == 1) ? 48 : 16, sL0 = (wl == 1) ? 16 : 0;
        const int nR = (wr == 1) ? 48 : 16, sR0 = (wr == 1) ? 16 : 0;
        const float shift = ((wl == 1) ? 0.f : sMaxL0[hh]) + sShR0;
        float part = 0.f;
        const float* rb = rule + (size_t)(((b * NTv + A) * Nv + h) * Tv) * Tv * 2;
        for (int i = sub; i < nL; i += 2) {
          const float cl = (wl == 1) ? 0.f : sCL0[i * Nv + hh];
          const float* rp = rb + (size_t)(sL0 + i) * Tv * 2 + sR0 * 2;
#pragma unroll 8
          for (int j = 0; j < nR; ++j) part += __expf(cl + sER0[j] + rp[j * 2]);
        }
        float nm = fmaxf(runM, shift);
        runS = runS * __expf(runM - nm) + part * __expf(shift - nm);
        runM = nm;
      }
      if (hh >= wl && (wr > 1 || hh == W - 1)) {
        const int nL = (wl == 1) ? 48 : 16, sL0 = (wl == 1) ? 16 : 0;
        const int nR = (wr == 1) ? 48 : 16, sR0 = (wr == 1) ? 16 : 0;
        const float shift = sShL1 + ((wr == 1) ? 0.f : sMaxR1[hh]);
        float part = 0.f;
        const float* rb = rule + (size_t)(((b * NTv + A) * Nv + h) * Tv) * Tv * 2 + 1;
        for (int i = sub; i < nL; i += 2) {
          const float el = sEL1[i];
          const float* rp = rb + (size_t)(sL0 + i) * Tv * 2 + sR0 * 2;
#pragma unroll 8
          for (int j = 0; j < nR; ++j) {
            const float cr = (wr == 1) ? 0.f : sCR1[j * Nv + hh];
            part += __expf(el + cr + rp[j * 2]);
          }
        }
        float nm = fmaxf(runM, shift);
        runS = runS * __expf(runM - nm) + part * __expf(shift - nm);
        runM = nm;
      }
    }
    __syncthreads();
  }
  if (act) {
    float om = __shfl_xor(runM, 1, 64);
    float os = __shfl_xor(runS, 1, 64);
    float nm = fmaxf(runM, om);
    float s = runS * __expf(runM - nm) + os * __expf(om - nm);
    if (sub == 0) {
      float val = nm + __logf(s);
      betaA[(size_t)((b * NP + l) * NP + r) * 384 + A * Nv + h] = val;
      sTmp[A * Nv + hh] = val + unary[(b * Nv + h) * Tv + A];
    }
  }
  __syncthreads();
  if (tid < 16) {
    float mx = NEGF;
    for (int x = 0; x < W; ++x) mx = fmaxf(mx, sTmp[tid * Nv + x]);
    float s = 0.f;
    for (int x = 0; x < W; ++x) s += __expf(sTmp[tid * Nv + x] - mx);
    betau[(size_t)((b * NP + l) * NP + r) * Tv + tid] = mx + __logf(s);
  }
}

__global__ void final_kernel(const float* __restrict__ betau, const float* __restrict__ root,
                             float* __restrict__ out) {
  int b = threadIdx.x;
  if (b < Bv) {
    float vals[NTv];
    float mx = NEGF;
#pragma unroll
    for (int A = 0; A < NTv; ++A) {
      float v = betau[(size_t)((b * NP + 0) * NP + Nv) * Tv + A] + root[b * NTv + A];
      vals[A] = v;
      mx = fmaxf(mx, v);
    }
    float s = 0.f;
#pragma unroll
    for (int A = 0; A < NTv; ++A) s += __expf(vals[A] - mx);
    out[b] = mx + __logf(s);
  }
}

extern "C" void kernel_launch(void* const* d_in, const int* in_sizes, int n_in,
                              void* d_out, int out_size, void* d_ws, size_t ws_size,
                              hipStream_t stream) {
  (void)in_sizes; (void)n_in; (void)out_size;
  const float* unary = (const float*)d_in[0];
  const float* rule  = (const float*)d_in[1];
  const float* root  = (const float*)d_in[2];
  float* out = (float*)d_out;
  float* ws = (float*)d_ws;
  float* betaA = ws + BETAA_OFF;
  float* betau = ws + BETAU_OFF;
  const bool fast = ws_size >= (size_t)WS_NEED * sizeof(float);

  if (fast) {
    unsigned* RNTh = (unsigned*)(ws + RNT_OFF);
    float* T0  = ws + T0_OFF;
    float* T1  = ws + T1_OFF;
    float* T0L = ws + T0L_OFF;
    float* T1R = ws + T1R_OFF;
    float* D0  = ws + D0_OFF;
    float* D1  = ws + D1_OFF;
    float* Eu  = ws + EU_OFF;
    int* cellF = (int*)(ws + CELLF_OFF);
    init_kernel<<<(Bv * Nv * 48 + 255) / 256, 256, 0, stream>>>(unary, betau, Eu, cellF);
    prep_kernel<<<dim3(24, 16, 4), 256, 0, stream>>>(rule, Eu, RNTh, T0, T1, T0L, T1R, D0, D1);
    void* args[] = {(void*)&unary, (void*)&betaA, (void*)&betau, (void*)&RNTh,
                    (void*)&T0, (void*)&T1, (void*)&T0L, (void*)&T1R,
                    (void*)&D0, (void*)&D1, (void*)&root, (void*)&out, (void*)&cellF};
    hipLaunchCooperativeKernel((const void*)width_all_kernel, dim3(12, Bv), dim3(768),
                               args, 0, stream);
  } else {
    float* Eu = ws + BETAU_OFF + 160000;  // reuse space past betau for Eu in fallback
    int* prog = (int*)(ws + BETAU_OFF + 160000 + 4608);
    init_kernel<<<(Bv * Nv * 48 + 255) / 256, 256, 0, stream>>>(unary, betau, Eu, prog);
    for (int W = 2; W <= Nv; ++W) {
      dim3 grid(Nv - W + 1, Bv);
      width_kernel_fb<<<grid, 768, 0, stream>>>(unary, rule, betaA, betau, W);
    }
    final_kernel<<<1, 64, 0, stream>>>(betau, root, out);
  }
}

// Round 14
// 396.880 us; speedup vs baseline: 1.6231x; 1.6231x over previous
//
#include <hip/hip_runtime.h>
#include <cstddef>

#define Bv 4
#define Nv 24
#define NTv 16
#define Tv 64
#define NP 25
#define NEGF (-1e30f)

typedef __attribute__((ext_vector_type(8))) short short8v;
typedef __attribute__((ext_vector_type(4))) float f32x4;
union FragU { unsigned u[4]; short8v s; };

// ---------------- workspace layout (floats) ----------------
// betaA layout: [B][25 l][25 r][24 head][16 sym]  (head-major for coalesced lane reads)
#define BETAA_OFF 0         // [B][25][25][24 head][16 sym]            960000
#define BETAU_OFF 960000    // [B][25][25][64 sym]                     160000
#define RNT_OFF   1120000   // bf16-packed: [B][2 d][24 h][16 A][128]  u32
#define T0_OFF    1906432   // [B][24 h][24 p][16 sL][16 A]            589824
#define T1_OFF    2496256   // [B][24 h][24 p][16 sR][16 A]            589824
#define T0L_OFF   3086080   // [B][24 h][16 sR][16 A]                  24576
#define T1R_OFF   3110656   // [B][24 h][16 sL][16 A]                  24576
#define D0_OFF    3135232   // [B][24 l][16 A]                         1536
#define D1_OFF    3136768   // [B][24 l][16 A]                         1536
#define EU_OFF    3138304   // [B][24 p][48 j]  exp(unary terminal)    4608
#define CELLF_OFF 3142912   // [B][25*25] int per-cell done flags      2500
#define WS_NEED   3145412

// sweep-free publication (R10-verified): relaxed agent-scope atomic store lands
// the value at the device coherence point; readers first-touch after the flag.
__device__ __forceinline__ void publish(float* p, float v) {
  __hip_atomic_store(p, v, __ATOMIC_RELAXED, __HIP_MEMORY_SCOPE_AGENT);
}

__device__ __forceinline__ unsigned packbf2(float lo, float hi) {
  unsigned bl = __float_as_uint(lo), bh = __float_as_uint(hi);
  bl = (bl + 0x7FFFu + ((bl >> 16) & 1u)) >> 16;   // RNE
  bh = (bh + 0x7FFFu + ((bh >> 16) & 1u)) >> 16;
  return (bh << 16) | bl;
}

// ---- init: width-1 betau + exp(unary) table + cell flags ----
__global__ void init_kernel(const float* __restrict__ unary, float* __restrict__ betau,
                            float* __restrict__ Eu, int* __restrict__ cellF) {
  int t = blockIdx.x * blockDim.x + threadIdx.x;
  if (t < Bv * NP * NP) cellF[t] = 0;
  if (t >= Bv * Nv * 48) return;
  int i = t % 48, kk = (t / 48) % Nv, b = t / (48 * Nv);
  float u = unary[(size_t)(b * Nv + kk) * Tv + 16 + i];
  betau[((size_t)(b * NP + kk) * NP + (kk + 1)) * Tv + 16 + i] = u;
  Eu[(size_t)(b * Nv + kk) * 48 + i] = __expf(u);
}

// ---- fused prep: block per (b,A,h); coalesced 32KB rule read; all precontractions ----
__global__ __launch_bounds__(256) void prep_kernel(
    const float* __restrict__ rule, const float* __restrict__ Eu,
    unsigned* __restrict__ RNTh, float* __restrict__ T0, float* __restrict__ T1,
    float* __restrict__ T0L, float* __restrict__ T1R,
    float* __restrict__ D0, float* __restrict__ D1) {
  const int h = blockIdx.x, A = blockIdx.y, b = blockIdx.z;
  const int t = threadIdx.x;  // 256
  __shared__ float er0[64 * 65];  // exp(rule[..,sL,sR,0]), padded rows
  __shared__ float er1[64 * 65];
  __shared__ float E[24 * 48];
  __shared__ float red[256];

  for (int i = t; i < 24 * 48; i += 256) E[i] = Eu[(size_t)b * (24 * 48) + i];
  const float* rb = rule + (size_t)((b * NTv + A) * Nv + h) * 8192;
#pragma unroll
  for (int i = 0; i < 8; ++i) {
    int lin = i * 1024 + t * 4;  // = sL*128 + sR*2 + d
    float4 v = *(const float4*)(rb + lin);
    int sL = lin >> 7, rem = (lin & 127) >> 1;
    er0[sL * 65 + rem] = __expf(v.x);
    er1[sL * 65 + rem] = __expf(v.y);
    er0[sL * 65 + rem + 1] = __expf(v.z);
    er1[sL * 65 + rem + 1] = __expf(v.w);
  }
  __syncthreads();
  // RNTh (A-major, bf16 pairs over sR): [b][d][h][A][sL*8 + sRp]
  {
    unsigned* dst0 = RNTh + (((size_t)(b * 2 + 0) * Nv + h) * NTv + A) * 128;
    unsigned* dst1 = RNTh + (((size_t)(b * 2 + 1) * Nv + h) * NTv + A) * 128;
    if (t < 128) {
      int sL = t >> 3, sRp = t & 7;
      dst0[t] = packbf2(er0[sL * 65 + 2 * sRp], er0[sL * 65 + 2 * sRp + 1]);
    } else {
      int t2 = t - 128;
      int sL = t2 >> 3, sRp = t2 & 7;
      dst1[t2] = packbf2(er1[sL * 65 + 2 * sRp], er1[sL * 65 + 2 * sRp + 1]);
    }
  }
  // T0[b,h,p,sL,A] = sum_j E[p][j]*er0[sL][16+j]
  for (int o = t; o < 384; o += 256) {
    int p = o >> 4, sL = o & 15;
    const float* Ep = E + p * 48;
    const float* r0 = er0 + sL * 65 + 16;
    float acc = 0.f;
#pragma unroll 8
    for (int j = 0; j < 48; ++j) acc += Ep[j] * r0[j];
    T0[(((size_t)(b * Nv + h) * Nv + p) * NTv + sL) * NTv + A] = acc;
  }
  // T1[b,h,p,sR,A] = sum_i E[p][i]*er1[16+i][sR]
  for (int o = t; o < 384; o += 256) {
    int p = o >> 4, sR = o & 15;
    const float* Ep = E + p * 48;
    float acc = 0.f;
#pragma unroll 8
    for (int i = 0; i < 48; ++i) acc += Ep[i] * er1[(16 + i) * 65 + sR];
    T1[(((size_t)(b * Nv + h) * Nv + p) * NTv + sR) * NTv + A] = acc;
  }
  if (t < 16) {  // T0L[b,h,sR,A] = sum_i er0[16+i][sR]
    float acc = 0.f;
    for (int i = 0; i < 48; ++i) acc += er0[(16 + i) * 65 + t];
    T0L[((size_t)(b * Nv + h) * NTv + t) * NTv + A] = acc;
  } else if (t < 32) {  // T1R[b,h,sL,A] = sum_j er1[sL][16+j]
    int sL = t - 16;
    float acc = 0.f;
    for (int j = 0; j < 48; ++j) acc += er1[sL * 65 + 16 + j];
    T1R[((size_t)(b * Nv + h) * NTv + sL) * NTv + A] = acc;
  }
  // D0[b,l=h,A] = sum_{i,j} E[h+1][j]*er0[16+i][16+j];  D1[b,l=h-1,A] likewise
  float acc0 = 0.f, acc1 = 0.f;
  const int hp = (h + 1 < 24) ? h + 1 : 0, hm = (h >= 1) ? h - 1 : 0;
  for (int e = t; e < 2304; e += 256) {
    int i = e / 48, j = e % 48;
    float r0 = er0[(16 + i) * 65 + 16 + j];
    float r1 = er1[(16 + i) * 65 + 16 + j];
    acc0 += E[hp * 48 + j] * r0;
    acc1 += E[hm * 48 + i] * r1;
  }
  red[t] = acc0;
  __syncthreads();
  if (t < 64) {
    float s = red[t] + red[t + 64] + red[t + 128] + red[t + 192];
#pragma unroll
    for (int off = 32; off; off >>= 1) s += __shfl_xor(s, off, 64);
    if (t == 0 && h <= 22) D0[((size_t)b * Nv + h) * NTv + A] = s;
  }
  __syncthreads();
  red[t] = acc1;
  __syncthreads();
  if (t < 64) {
    float s = red[t] + red[t + 64] + red[t + 128] + red[t + 192];
#pragma unroll
    for (int off = 32; off; off >>= 1) s += __shfl_xor(s, off, 64);
    if (t == 0 && h >= 1) D1[((size_t)b * Nv + (h - 1)) * NTv + A] = s;
  }
}

__device__ __forceinline__ void edge_dot(float v0, float v1, float v2, float v3,
                                         const float* Tb, float& sh, float& S) {
  float mx = fmaxf(fmaxf(v0, v1), fmaxf(v2, v3));
  mx = fmaxf(mx, __shfl_xor(mx, 1, 64));
  mx = fmaxf(mx, __shfl_xor(mx, 2, 64));
  float dot = __expf(v0 - mx) * Tb[0] + __expf(v1 - mx) * Tb[16] +
              __expf(v2 - mx) * Tb[32] + __expf(v3 - mx) * Tb[48];
  dot += __shfl_xor(dot, 1, 64);
  dot += __shfl_xor(dot, 2, 64);
  sh = mx;
  S = dot;
}

// ---- column-per-block persistent kernel (R11 base) with MFMA cell body ----
// Phase A per (head,dir): U = E_L . E_R^T as ONE mfma_f32_16x16x32_bf16.
// Phase B per (head,dir): acc[A] = sum_x RNT[A,x] U[x] as 8 chained MFMAs.
// Epilogue micro-opts this round: unary cached in LDS (no global load inside
// the critical epilogue); betau logsumexp wave-parallel (<=6 exps/lane vs 24).
__global__ __launch_bounds__(768) void width_all_kernel(
    const float* __restrict__ unary, float* __restrict__ betaA, float* __restrict__ betau,
    const unsigned* __restrict__ RNTh, const float* __restrict__ T0, const float* __restrict__ T1,
    const float* __restrict__ T0L, const float* __restrict__ T1R,
    const float* __restrict__ D0, const float* __restrict__ D1,
    const float* __restrict__ root, float* __restrict__ out, int* __restrict__ cellF) {
  const int rr = blockIdx.x, b = blockIdx.y;
  const int r = rr + 2;
  const int tid = threadIdx.x;
  int* flagb = cellF + b * (NP * NP);

  __shared__ float chartC[23][384];  // own column cells (l',r): [l'][head*16+sym]
  __shared__ float buC[23][16];      // own column betau NT: [l'][sym]
  __shared__ float U0[24 * 256], U1[24 * 256];
  __shared__ float pM[2 * 24 * 16], pS[2 * 24 * 16];
  __shared__ float sTmp[16 * 24];
  __shared__ float uC[24][16];       // unary NT slice for this batch

  if (tid < 384) uC[tid >> 4][tid & 15] =
      unary[(size_t)(b * Nv + (tid >> 4)) * Tv + (tid & 15)];
  // ordered before first use (combine stage) by the pM/pS barrier of cell 0

  const int wv = tid >> 6, lane = tid & 63;
  const int sym = lane & 15;          // A-row / B-col index
  const int mBlk = (lane >> 4) * 8;   // k-offset of this lane's 8 elements

  for (int i = 0; i <= r - 2; ++i) {
    const int l = r - 2 - i;
    const int W = r - l;  // = i + 2

    if (W >= 3) {
      // interior deps (slack >= 1): cells (l, m) for m in [l+2, r-2]
      if (tid < W - 3) {
        const int m = l + 2 + tid;
        while (__hip_atomic_load(&flagb[l * NP + m], __ATOMIC_RELAXED,
                                 __HIP_MEMORY_SCOPE_AGENT) == 0)
          __builtin_amdgcn_s_sleep(1);
      }
      __syncthreads();  // also orders prev cell's chartC/buC epilogue writes
    }

    float Gp[4];
    // ---- Phase A (per-wave pairs): gather, global-max shift, exp, 1 MFMA ----
#pragma unroll
    for (int pi = 0; pi < 4; ++pi) {
      const int p = wv + 12 * pi;
      if (p < 2 * W) {
        const int hh = p >> 1, d = p & 1, hcol = l + hh;
        int mst, cnt;
        if (d) { mst = l + 2; cnt = min(l + hh, r - 2) - mst + 1; }
        else   { mst = max(l + hh + 1, l + 2); cnt = (r - 2) - mst + 1; }
        if (cnt < 0) cnt = 0;
        float* Ua = (d ? U1 : U0) + hh * 256;
        if (cnt == 0) {
#pragma unroll
          for (int reg = 0; reg < 4; ++reg)
            Ua[((lane >> 4) * 4 + reg) * 16 + sym] = 0.f;
          Gp[pi] = -2e30f;
        } else {
          float Lv[8], Rv[8];
          if (d) {  // L = betau(l,m)[sym], R = chart(m,r)[hcol][sym] (own LDS)
            const size_t lb = ((size_t)(b * NP + l) * NP + mst) * Tv + sym;
#pragma unroll
            for (int j = 0; j < 8; ++j) {
              int mi = mBlk + j;
              Lv[j] = (mi < cnt) ? betau[lb + (size_t)mi * Tv] : NEGF;
              Rv[j] = (mi < cnt) ? chartC[mst + mi][hcol * 16 + sym] : NEGF;
            }
          } else {  // L = chart(l,m)[hcol][sym] (global row), R = betau(m,r)[sym] (own LDS)
            const size_t lb = ((size_t)(b * NP + l) * NP + mst) * 384 + hcol * 16 + sym;
#pragma unroll
            for (int j = 0; j < 8; ++j) {
              int mi = mBlk + j;
              Lv[j] = (mi < cnt) ? betaA[lb + (size_t)mi * 384] : NEGF;
              Rv[j] = (mi < cnt) ? buC[mst + mi][sym] : NEGF;
            }
          }
          float mxL = NEGF, mxR = NEGF;
#pragma unroll
          for (int j = 0; j < 8; ++j) { mxL = fmaxf(mxL, Lv[j]); mxR = fmaxf(mxR, Rv[j]); }
#pragma unroll
          for (int off = 1; off < 64; off <<= 1) {
            mxL = fmaxf(mxL, __shfl_xor(mxL, off, 64));
            mxR = fmaxf(mxR, __shfl_xor(mxR, off, 64));
          }
          FragU fa, fb;
#pragma unroll
          for (int jj = 0; jj < 4; ++jj) {
            int m0i = mBlk + 2 * jj, m1i = m0i + 1;
            float e0 = (m0i < cnt) ? __expf(Lv[2 * jj] - mxL) : 0.f;
            float e1 = (m1i < cnt) ? __expf(Lv[2 * jj + 1] - mxL) : 0.f;
            fa.u[jj] = packbf2(e0, e1);
            float f0 = (m0i < cnt) ? __expf(Rv[2 * jj] - mxR) : 0.f;
            float f1 = (m1i < cnt) ? __expf(Rv[2 * jj + 1] - mxR) : 0.f;
            fb.u[jj] = packbf2(f0, f1);
          }
          f32x4 z = {0.f, 0.f, 0.f, 0.f};
          f32x4 dU = __builtin_amdgcn_mfma_f32_16x16x32_bf16(fa.s, fb.s, z, 0, 0, 0);
#pragma unroll
          for (int reg = 0; reg < 4; ++reg)
            Ua[((lane >> 4) * 4 + reg) * 16 + sym] = dU[reg];
          Gp[pi] = mxL + mxR;
        }
      }
    }

    // ---- slack-0 edge poll: cell (l, r-1) (per-thread spin, no barrier) ----
    if (W >= 3) {
      while (__hip_atomic_load(&flagb[l * NP + (r - 1)], __ATOMIC_RELAXED,
                               __HIP_MEMORY_SCOPE_AGENT) == 0)
        __builtin_amdgcn_s_sleep(1);
    }

    // ---- Phase B (same wave, same pairs): 8-MFMA matvec + edges ----
#pragma unroll
    for (int pi = 0; pi < 4; ++pi) {
      const int p = wv + 12 * pi;
      if (p < 2 * W) {
        const int hh = p >> 1, d = p & 1, h = l + hh;
        const float* Ua = (d ? U1 : U0) + hh * 256;
        const unsigned* Rb = RNTh + (((size_t)(b * 2 + d) * Nv + h) * NTv + sym) * 128;
        f32x4 acc4 = {0.f, 0.f, 0.f, 0.f};
#pragma unroll
        for (int kk = 0; kk < 8; ++kk) {
          uint4 ar = *(const uint4*)(Rb + kk * 16 + (lane >> 4) * 4);
          FragU fa, fb;
          fa.u[0] = ar.x; fa.u[1] = ar.y; fa.u[2] = ar.z; fa.u[3] = ar.w;
          if (sym == 0) {
            const float* up = Ua + kk * 32 + mBlk;
#pragma unroll
            for (int jj = 0; jj < 4; ++jj) fb.u[jj] = packbf2(up[2 * jj], up[2 * jj + 1]);
          } else {
            fb.u[0] = 0; fb.u[1] = 0; fb.u[2] = 0; fb.u[3] = 0;
          }
          acc4 = __builtin_amdgcn_mfma_f32_16x16x32_bf16(fa.s, fb.s, acc4, 0, 0, 0);
        }
        // broadcast acc[A] (rows live in col-0 lanes) to (A,q) edge layout
        const int A = lane >> 2, q = lane & 3;
        const int src = (A >> 2) << 4;
        float c0 = __shfl(acc4[0], src, 64);
        float c1 = __shfl(acc4[1], src, 64);
        float c2 = __shfl(acc4[2], src, 64);
        float c3 = __shfl(acc4[3], src, 64);
        const int sel = A & 3;
        float acc = (sel == 0) ? c0 : (sel == 1) ? c1 : (sel == 2) ? c2 : c3;
        float Mi = Gp[pi];
        float sh2 = NEGF, S2 = 0.f, sh3 = NEGF, S3 = 0.f;
        if (W >= 3) {
          if (d == 0) {
            if (hh < W - 1) {  // split m=r-1: chart(l,r-1) x terminal via T0 (global row)
              const float* Tb = T0 + (((size_t)(b * Nv + h) * Nv + (r - 1)) * NTv + 4 * q) * NTv + A;
              float4 e4 = *(const float4*)(betaA +
                  ((size_t)(b * NP + l) * NP + (r - 1)) * 384 + (size_t)h * 16 + 4 * q);
              edge_dot(e4.x, e4.y, e4.z, e4.w, Tb, sh2, S2);
            }
            if (hh == 0) {     // split m=l+1: terminal x betau(l+1,r) via T0L (own, LDS)
              const float* Tb = T0L + ((size_t)(b * Nv + l) * NTv + 4 * q) * NTv + A;
              const float* u4 = &buC[l + 1][4 * q];
              edge_dot(u4[0], u4[1], u4[2], u4[3], Tb, sh3, S3);
            }
          } else {
            if (hh >= 1) {     // split m=l+1: terminal x chart(l+1,r) via T1 (own, LDS)
              const float* Tb = T1 + (((size_t)(b * Nv + h) * Nv + l) * NTv + 4 * q) * NTv + A;
              const float* e4 = &chartC[l + 1][h * 16 + 4 * q];
              edge_dot(e4[0], e4[1], e4[2], e4[3], Tb, sh2, S2);
            }
            if (hh == W - 1) { // split m=r-1: betau(l,r-1) x terminal via T1R (global row)
              const float* Tb = T1R + ((size_t)(b * Nv + (r - 1)) * NTv + 4 * q) * NTv + A;
              float4 u4 = *(const float4*)(betau +
                  ((size_t)(b * NP + l) * NP + (r - 1)) * Tv + 4 * q);
              edge_dot(u4.x, u4.y, u4.z, u4.w, Tb, sh3, S3);
            }
          }
        } else {  // W == 2
          if (d == 0 && hh == 0) { sh2 = 0.f; S2 = D0[((size_t)b * Nv + l) * NTv + A]; }
          if (d == 1 && hh == 1) { sh2 = 0.f; S2 = D1[((size_t)b * Nv + l) * NTv + A]; }
        }
        float Mf = fmaxf(Mi, fmaxf(sh2, sh3));
        float Sf = acc * __expf(Mi - Mf) + S2 * __expf(sh2 - Mf) + S3 * __expf(sh3 - Mf);
        if (q == 0) {
          pM[(d * 24 + hh) * 16 + A] = Mf;
          pS[(d * 24 + hh) * 16 + A] = Sf;
        }
      }
    }
    __syncthreads();

    // combine dirs; publish betaA + fill own chartC; prep betau input (LDS unary)
    if (tid < 384) {
      int A2 = tid & 15, hh = tid >> 4;
      if (hh < W) {
        float M0 = pM[(0 * 24 + hh) * 16 + A2], S0 = pS[(0 * 24 + hh) * 16 + A2];
        float M1 = pM[(1 * 24 + hh) * 16 + A2], S1 = pS[(1 * 24 + hh) * 16 + A2];
        float nm = fmaxf(M0, M1);
        float s = S0 * __expf(M0 - nm) + S1 * __expf(M1 - nm);
        float val = nm + __logf(s);
        publish(&betaA[((size_t)(b * NP + l) * NP + r) * 384 + (l + hh) * 16 + A2], val);
        chartC[l][(l + hh) * 16 + A2] = val;
        sTmp[A2 * 24 + hh] = val + uC[l + hh][A2];
      }
    }
    __syncthreads();  // sTmp ready; betaA publishes drained (implicit vmcnt(0))
    // wave-parallel betau logsumexp: 64 lanes = 16 A x 4 head-groups
    if (tid < 64) {
      const int A2 = tid & 15, g4 = tid >> 4;
      float mx = NEGF;
      for (int x = g4; x < W; x += 4) mx = fmaxf(mx, sTmp[A2 * 24 + x]);
      mx = fmaxf(mx, __shfl_xor(mx, 16, 64));
      mx = fmaxf(mx, __shfl_xor(mx, 32, 64));
      float s = 0.f;
      for (int x = g4; x < W; x += 4) s += __expf(sTmp[A2 * 24 + x] - mx);
      s += __shfl_xor(s, 16, 64);
      s += __shfl_xor(s, 32, 64);
      if (g4 == 0) {
        float val = mx + __logf(s);
        publish(&betau[((size_t)(b * NP + l) * NP + r) * Tv + A2], val);
        buC[l][A2] = val;
      }
    }
    if (tid == 0) {
      asm volatile("s_waitcnt vmcnt(0)" ::: "memory");  // drain wave0 betau publishes
      __hip_atomic_store(&flagb[l * NP + r], 1, __ATOMIC_RELAXED,
                         __HIP_MEMORY_SCOPE_AGENT);
    }
  }

  // ---- final: column-24 block computes out[b] from its own cell (0,24) ----
  if (rr == 22) {
    __syncthreads();
    if (tid == 0) {
      float vals[NTv];
      float mx = NEGF;
#pragma unroll
      for (int A = 0; A < NTv; ++A) {
        float v = buC[0][A] + root[b * NTv + A];
        vals[A] = v;
        mx = fmaxf(mx, v);
      }
      float s = 0.f;
#pragma unroll
      for (int A = 0; A < NTv; ++A) s += __expf(vals[A] - mx);
      out[b] = mx + __logf(s);
    }
  }
}

// ---- fallback width kernel (direct rule reads, self-consistent layout) ----
__global__ __launch_bounds__(768) void width_kernel_fb(
    const float* __restrict__ unary, const float* __restrict__ rule,
    float* __restrict__ betaA, float* __restrict__ betau, int W) {
  const int l = blockIdx.x, b = blockIdx.y;
  const int r = l + W;
  const int tid = threadIdx.x;
  const int sub = tid & 1;
  const int pid = tid >> 1;
  const int A = pid & 15;
  const int hh = pid >> 4;
  const int h = l + hh;
  const bool act = (hh < W);
  const int sA = tid & 15, sH = tid >> 4;

  __shared__ float sER0[48], sEL1[48];
  __shared__ float sCL0[16 * 24], sCR1[16 * 24];
  __shared__ float sMaxL0[24], sMaxR1[24];
  __shared__ float sShR0, sShL1;
  __shared__ float sTmp[16 * 24];

  float runM = NEGF, runS = 0.f;
  for (int m = l + 1; m < r; ++m) {
    const int wl = m - l, wr = r - m;
    if (tid < 64) {
      const int n = (wr == 1) ? 48 : 16, s0 = (wr == 1) ? 16 : 0;
      float v = (tid < n) ? betau[(size_t)((b * NP + m) * NP + r) * Tv + s0 + tid] : NEGF;
      float mx = v;
#pragma unroll
      for (int off = 32; off; off >>= 1) mx = fmaxf(mx, __shfl_xor(mx, off, 64));
      if (tid == 0) sShR0 = mx;
      if (tid < n) sER0[tid] = v - mx;
    } else if (tid < 128) {
      const int j = tid - 64;
      const int n = (wl == 1) ? 48 : 16, s0 = (wl == 1) ? 16 : 0;
      float v = (j < n) ? betau[(size_t)((b * NP + l) * NP + m) * Tv + s0 + j] : NEGF;
      float mx = v;
#pragma unroll
      for (int off = 32; off; off >>= 1) mx = fmaxf(mx, __shfl_xor(mx, off, 64));
      if (j == 0) sShL1 = mx;
      if (j < n) sEL1[j] = v - mx;
    }
    if (tid < 384) {
      if (wl > 1 && sH < wl) {
        float v = betaA[(size_t)((b * NP + l) * NP + m) * 384 + sA * Nv + (l + sH)];
        float mx = v;
#pragma unroll
        for (int off = 8; off; off >>= 1) mx = fmaxf(mx, __shfl_xor(mx, off, 16));
        if (sA == 0) sMaxL0[sH] = mx;
        sCL0[sA * Nv + sH] = v - mx;
      }
      if (wr > 1 && sH >= wl && sH < W) {
        float v = betaA[(size_t)((b * NP + m) * NP + r) * 384 + sA * Nv + (l + sH)];
        float mx = v;
#pragma unroll
        for (int off = 8; off; off >>= 1) mx = fmaxf(mx, __shfl_xor(mx, off, 16));
        if (sA == 0) sMaxR1[sH] = mx;
        sCR1[sA * Nv + sH] = v - mx;
      }
    }
    __syncthreads();
    if (act) {
      if (hh < wl && (wl > 1 || hh == 0)) {
        const int nL = (wl == 1) ? 48 : 16, sL0 = (wl == 1) ? 16 : 0;
        const int nR = (wr == 1) ? 48 : 16, sR0 = (wr == 1) ? 16 : 0;
        const float shift = ((wl == 1) ? 0.f : sMaxL0[hh]) + sShR0;
        float part = 0.f;
        const float* rb = rule + (size_t)(((b * NTv + A) * Nv + h) * Tv) * Tv * 2;
        for (int i = sub; i < nL; i += 2) {
          const float cl = (wl == 1) ? 0.f : sCL0[i * Nv + hh];
          const float* rp = rb + (size_t)(sL0 + i) * Tv * 2 + sR0 * 2;
#pragma unroll 8
          for (int j = 0; j < nR; ++j) part += __expf(cl + sER0[j] + rp[j * 2]);
        }
        float nm = fmaxf(runM, shift);
        runS = runS * __expf(runM - nm) + part * __expf(shift - nm);
        runM = nm;
      }
      if (hh >= wl && (wr > 1 || hh == W - 1)) {
        const int nL = (wl == 1) ? 48 : 16, sL0 = (wl == 1) ? 16 : 0;
        const int nR = (wr == 1) ? 48 : 16, sR0 = (wr == 1) ? 16 : 0;
        const float shift = sShL1 + ((wr == 1) ? 0.f : sMaxR1[hh]);
        float part = 0.f;
        const float* rb = rule + (size_t)(((b * NTv + A) * Nv + h) * Tv) * Tv * 2 + 1;
        for (int i = sub; i < nL; i += 2) {
          const float el = sEL1[i];
          const float* rp = rb + (size_t)(sL0 + i) * Tv * 2 + sR0 * 2;
#pragma unroll 8
          for (int j = 0; j < nR; ++j) {
            const float cr = (wr == 1) ? 0.f : sCR1[j * Nv + hh];
            part += __expf(el + cr + rp[j * 2]);
          }
        }
        float nm = fmaxf(runM, shift);
        runS = runS * __expf(runM - nm) + part * __expf(shift - nm);
        runM = nm;
      }
    }
    __syncthreads();
  }
  if (act) {
    float om = __shfl_xor(runM, 1, 64);
    float os = __shfl_xor(runS, 1, 64);
    float nm = fmaxf(runM, om);
    float s = runS * __expf(runM - nm) + os * __expf(om - nm);
    if (sub == 0) {
      float val = nm + __logf(s);
      betaA[(size_t)((b * NP + l) * NP + r) * 384 + A * Nv + h] = val;
      sTmp[A * Nv + hh] = val + unary[(b * Nv + h) * Tv + A];
    }
  }
  __syncthreads();
  if (tid < 16) {
    float mx = NEGF;
    for (int x = 0; x < W; ++x) mx = fmaxf(mx, sTmp[tid * Nv + x]);
    float s = 0.f;
    for (int x = 0; x < W; ++x) s += __expf(sTmp[tid * Nv + x] - mx);
    betau[(size_t)((b * NP + l) * NP + r) * Tv + tid] = mx + __logf(s);
  }
}

__global__ void final_kernel(const float* __restrict__ betau, const float* __restrict__ root,
                             float* __restrict__ out) {
  int b = threadIdx.x;
  if (b < Bv) {
    float vals[NTv];
    float mx = NEGF;
#pragma unroll
    for (int A = 0; A < NTv; ++A) {
      float v = betau[(size_t)((b * NP + 0) * NP + Nv) * Tv + A] + root[b * NTv + A];
      vals[A] = v;
      mx = fmaxf(mx, v);
    }
    float s = 0.f;
#pragma unroll
    for (int A = 0; A < NTv; ++A) s += __expf(vals[A] - mx);
    out[b] = mx + __logf(s);
  }
}

extern "C" void kernel_launch(void* const* d_in, const int* in_sizes, int n_in,
                              void* d_out, int out_size, void* d_ws, size_t ws_size,
                              hipStream_t stream) {
  (void)in_sizes; (void)n_in; (void)out_size;
  const float* unary = (const float*)d_in[0];
  const float* rule  = (const float*)d_in[1];
  const float* root  = (const float*)d_in[2];
  float* out = (float*)d_out;
  float* ws = (float*)d_ws;
  float* betaA = ws + BETAA_OFF;
  float* betau = ws + BETAU_OFF;
  const bool fast = ws_size >= (size_t)WS_NEED * sizeof(float);

  if (fast) {
    unsigned* RNTh = (unsigned*)(ws + RNT_OFF);
    float* T0  = ws + T0_OFF;
    float* T1  = ws + T1_OFF;
    float* T0L = ws + T0L_OFF;
    float* T1R = ws + T1R_OFF;
    float* D0  = ws + D0_OFF;
    float* D1  = ws + D1_OFF;
    float* Eu  = ws + EU_OFF;
    int* cellF = (int*)(ws + CELLF_OFF);
    init_kernel<<<(Bv * Nv * 48 + 255) / 256, 256, 0, stream>>>(unary, betau, Eu, cellF);
    prep_kernel<<<dim3(24, 16, 4), 256, 0, stream>>>(rule, Eu, RNTh, T0, T1, T0L, T1R, D0, D1);
    void* args[] = {(void*)&unary, (void*)&betaA, (void*)&betau, (void*)&RNTh,
                    (void*)&T0, (void*)&T1, (void*)&T0L, (void*)&T1R,
                    (void*)&D0, (void*)&D1, (void*)&root, (void*)&out, (void*)&cellF};
    hipLaunchCooperativeKernel((const void*)width_all_kernel, dim3(Nv - 1, Bv), dim3(768),
                               args, 0, stream);
  } else {
    float* Eu = ws + BETAU_OFF + 160000;  // reuse space past betau for Eu in fallback
    int* prog = (int*)(ws + BETAU_OFF + 160000 + 4608);
    init_kernel<<<(Bv * Nv * 48 + 255) / 256, 256, 0, stream>>>(unary, betau, Eu, prog);
    for (int W = 2; W <= Nv; ++W) {
      dim3 grid(Nv - W + 1, Bv);
      width_kernel_fb<<<grid, 768, 0, stream>>>(unary, rule, betaA, betau, W);
    }
    final_kernel<<<1, 64, 0, stream>>>(betau, root, out);
  }
}